// Round 3
// baseline (281.961 us; speedup 1.0000x reference)
//
#include <hip/hip_runtime.h>
#include <hip/hip_bf16.h>

#define NB 16
#define NA 1614
#define NBP (NB * 196 * 128)   // p1 slab stride = 401408

typedef __bf16 bf16x8 __attribute__((ext_vector_type(8)));
typedef float f32x4 __attribute__((ext_vector_type(4)));

__device__ __forceinline__ unsigned short f2bf(float v) {
  unsigned u = __float_as_uint(v);
  unsigned r = (u + 0x7FFFu + ((u >> 16) & 1u)) >> 16;
  return (unsigned short)r;
}
__device__ __forceinline__ float bf2f(unsigned short s) {
  return __uint_as_float(((unsigned)s) << 16);
}

// ---------------- prep (fused): blocks [0,1024) transpose+split rpn -> aT; rest -> wT ------
// aT layout: [chunk = b*64 + ic32grp][pos196][ic32] hi/lo, written fully coalesced (pos-major).
// wT layout: [kc16][tap9][ks4][oc128][icq4][8] hi/lo -> conv1 B-fragment reads are
// fully coalesced 1KB/wave global loads (no B LDS staging needed).
__global__ __launch_bounds__(256)
void prep(const float* __restrict__ w, const float* __restrict__ in,
          unsigned short* __restrict__ wTh, unsigned short* __restrict__ wTl,
          unsigned short* __restrict__ aTh, unsigned short* __restrict__ aTl) {
  __shared__ float s[32 * 201];
  const int bid = blockIdx.x;
  if (bid < 1024) {
    const int chunk = bid & 63, b = bid >> 6;
    const float* src = in + ((size_t)b * 2048 + chunk * 32) * 196;
#pragma unroll
    for (int r = 0; r < 7; r++) {
      int e = threadIdx.x + 256 * r;
      if (e < 1568) {
        int ic = e / 49, f = e - ic * 49;
        float4 v = ((const float4*)(src + (size_t)ic * 196))[f];
        float* d = s + ic * 201 + f * 4;
        d[0] = v.x; d[1] = v.y; d[2] = v.z; d[3] = v.w;
      }
    }
    __syncthreads();
    unsigned short* oh = aTh + (size_t)bid * (196 * 32);
    unsigned short* ol = aTl + (size_t)bid * (196 * 32);
#pragma unroll
    for (int r = 0; r < 4; r++) {
      int e = threadIdx.x + 256 * r;   // uint4 units; e = pos*4 + part -> contiguous writes
      if (e < 784) {
        int pos = e >> 2, part = e & 3;
        unsigned short hv[8], lv[8];
#pragma unroll
        for (int j = 0; j < 8; j++) {
          float v = s[(part * 8 + j) * 201 + pos];
          unsigned short h = f2bf(v);
          hv[j] = h;
          lv[j] = f2bf(v - bf2f(h));
        }
        ((uint4*)oh)[e] = *(uint4*)hv;
        ((uint4*)ol)[e] = *(uint4*)lv;
      }
    }
  } else {
    int e = (bid - 1024) * 256 + threadIdx.x;
    if (e < 9 * 128 * 2048) {
      int tap = e / (128 * 2048);
      int rem = e - tap * (128 * 2048);
      int oc = rem >> 11, ic = rem & 2047;
      // decompose ic = kc*128 + ks*32 + icq*8 + j
      int kcp = ic >> 7, ks = (ic >> 5) & 3, icq = (ic >> 3) & 3, j = ic & 7;
      size_t g2 = ((size_t)(kcp * 36 + tap * 4 + ks) << 12) + oc * 32 + icq * 8 + j;
      float v = w[((size_t)oc * 2048 + ic) * 9 + tap];
      unsigned short h = f2bf(v);
      wTh[g2] = h;
      wTl[g2] = f2bf(v - bf2f(h));
    }
  }
}

// ---------------- conv1 MFMA: implicit GEMM, split-bf16, wave-level K-split ----------------
// grid 256 = kc(16) x b(16), 1 block/CU. Block = 512 threads = 8 waves:
//   wq = wid&3 -> (wm,wn) output tile as before (wave tile M112 x N64, mf7 x nf4)
//   wk = wid>>2 -> K half: wk0 runs ks 0..1, wk1 runs ks 2..3 CONCURRENTLY.
// 2 waves/SIMD so one wave's LDS/VMEM waits overlap the other's MFMA issue
// (round-2 post-mortem: 1 wave/SIMD serialized LDS + MFMA -> 2x the 24.4us floor).
// Per-CU totals (MFMA, LDS reads, B loads) identical to round 2.
//  - B fragments loaded directly from global (L2-resident), register double-buffered.
//  - Per wk-half: own double-buffered A tile (4 buffers total, 140KB LDS).
//  - 3 barriers in main loop (prologue + each half's ks boundary, aligned).
//  - Epilogue: wk1 writes acc into freed A-LDS, wk0 adds (fixed order) and stores p1
//    -> p1 stays 16 slabs, downstream unchanged.
#define APL 2192          // ush per icq plane
#define ABUF (4 * APL)    // ush per A buffer (8768)

#define LOADB(H, L, T, K)                                                     \
  {                                                                           \
    const size_t o_ = ((size_t)(kc * 36 + (T) * 4 + (K)) << 12) + bln;        \
    const unsigned short* ph_ = wTh + o_;                                     \
    const unsigned short* pq_ = wTl + o_;                                     \
    H[0] = *(const bf16x8*)(ph_);                                             \
    H[1] = *(const bf16x8*)(ph_ + 512);                                       \
    H[2] = *(const bf16x8*)(ph_ + 1024);                                      \
    H[3] = *(const bf16x8*)(ph_ + 1536);                                      \
    L[0] = *(const bf16x8*)(pq_);                                             \
    L[1] = *(const bf16x8*)(pq_ + 512);                                       \
    L[2] = *(const bf16x8*)(pq_ + 1024);                                      \
    L[3] = *(const bf16x8*)(pq_ + 1536);                                      \
  }

#define STEP(IT, BUH, BUL, BNH, BNL)                                          \
  {                                                                           \
    const int it_ = (IT);                       /* local iter 0..17 */        \
    const int lks_ = it_ / 9, tap_ = it_ - lks_ * 9;                          \
    { /* prefetch next iter's B into the alternate register set */            \
      const int ni_ = (it_ < 17) ? it_ + 1 : 17;                              \
      const int nlk_ = ni_ / 9, nt_ = ni_ - nlk_ * 9;                         \
      LOADB(BNH, BNL, nt_, wk * 2 + nlk_);                                    \
    }                                                                         \
    if (lks_ == 0) { /* stage this half's 2nd ks: load taps 2..5, write 3..6 */ \
      const uint4* gh_ = (const uint4*)(aTh + ((size_t)(b * 64 + kc * 4 + wk * 2 + 1) * 196) * 32); \
      const uint4* gl_ = (const uint4*)(aTl + ((size_t)(b * 64 + kc * 4 + wk * 2 + 1) * 196) * 32); \
      if (tap_ >= 3 && tap_ <= 6) {                                           \
        int e_ = htid + 256 * (tap_ - 3);                                     \
        if (e_ < 784) {                                                       \
          int pos_ = e_ >> 2, part_ = e_ & 3;                                 \
          int py_ = pos_ / 14, px_ = pos_ - py_ * 14;                         \
          int d_ = abufbase + ABUF + part_ * APL + (py_ + 1) * 136 + (px_ + 1) * 8; \
          *(uint4*)(sAh + d_) = sgh;                                          \
          *(uint4*)(sAl + d_) = sgl;                                          \
        }                                                                     \
      }                                                                       \
      if (tap_ >= 2 && tap_ <= 5) {                                           \
        int e_ = htid + 256 * (tap_ - 2);                                     \
        if (e_ < 784) { sgh = gh_[e_]; sgl = gl_[e_]; }                       \
      }                                                                       \
    }                                                                         \
    const int t8_ = (tap_ / 3) * 136 + (tap_ - (tap_ / 3) * 3) * 8;           \
    const unsigned short* pah_ = sAh + abufbase + (lks_ & 1) * ABUF + qoff + t8_; \
    const unsigned short* pal_ = sAl + abufbase + (lks_ & 1) * ABUF + qoff + t8_; \
    bf16x8 afh[7], afl[7];                                                    \
    _Pragma("unroll") for (int mf = 0; mf < 7; mf++) {                        \
      afh[mf] = *(const bf16x8*)(pah_ + abase[mf]);                           \
      afl[mf] = *(const bf16x8*)(pal_ + abase[mf]);                           \
    }                                                                         \
    _Pragma("unroll") for (int mf = 0; mf < 7; mf++)                          \
      _Pragma("unroll") for (int nf = 0; nf < 4; nf++)                        \
        acc[mf][nf] = __builtin_amdgcn_mfma_f32_16x16x32_bf16(afh[mf], BUH[nf], acc[mf][nf], 0, 0, 0); \
    _Pragma("unroll") for (int mf = 0; mf < 7; mf++)                          \
      _Pragma("unroll") for (int nf = 0; nf < 4; nf++)                        \
        acc[mf][nf] = __builtin_amdgcn_mfma_f32_16x16x32_bf16(afl[mf], BUH[nf], acc[mf][nf], 0, 0, 0); \
    _Pragma("unroll") for (int mf = 0; mf < 7; mf++)                          \
      _Pragma("unroll") for (int nf = 0; nf < 4; nf++)                        \
        acc[mf][nf] = __builtin_amdgcn_mfma_f32_16x16x32_bf16(afh[mf], BUL[nf], acc[mf][nf], 0, 0, 0); \
    if (tap_ == 8) __syncthreads();                                           \
  }

__global__ __launch_bounds__(512, 2)
void conv1_mfma(const unsigned short* __restrict__ aTh, const unsigned short* __restrict__ aTl,
                const unsigned short* __restrict__ wTh, const unsigned short* __restrict__ wTl,
                float* __restrict__ p1) {
  const int bid = blockIdx.x;
  const int kc = bid & 15;
  const int b  = bid >> 4;
  const int tid = threadIdx.x;
  const int htid = tid & 255;
  const int wid = tid >> 6, lane = tid & 63;
  const int wq = wid & 3, wk = wid >> 2;
  const int wm = wq & 1, wn = wq >> 1;
  const int q = lane >> 4, ln = lane & 15;

  __shared__ unsigned short sAh[4 * ABUF];   // buffers: wk0 -> 0,1; wk1 -> 2,3
  __shared__ unsigned short sAl[4 * ABUF];
  const int abufbase = wk * (2 * ABUF);

  // zero all A buffers once: padded borders stay zero (stages overwrite interior only)
  for (int e = tid; e < 2 * ABUF; e += 512) {   // u32 units, 2*ABUF = 17536 per array
    ((unsigned int*)sAh)[e] = 0u;
    ((unsigned int*)sAl)[e] = 0u;
  }

  int abase[7];
#pragma unroll
  for (int mf = 0; mf < 7; mf++) {
    int row = wm * 112 + mf * 16 + ln;
    int y = row / 14, x = row - y * 14;
    abase[mf] = (row < 196) ? (y * 136 + x * 8) : 0;
  }
  const int qoff = q * APL;
  const int bln = (wn * 64 + ln) * 32 + q * 8;   // per-lane B offset (oc-major coalesced)

  f32x4 acc[7][4];
#pragma unroll
  for (int mf = 0; mf < 7; mf++)
#pragma unroll
    for (int nf = 0; nf < 4; nf++) acc[mf][nf] = (f32x4){0.f, 0.f, 0.f, 0.f};

  uint4 sgh, sgl;   // in-flight A staging registers (load tap t, LDS-write tap t+1)

  __syncthreads();   // zero-init complete before interior staging

  // prologue: each half stages its first ks into its buffer 0; load iter 0's B
  {
    const uint4* gh = (const uint4*)(aTh + ((size_t)(b * 64 + kc * 4 + wk * 2) * 196) * 32);
    const uint4* gl = (const uint4*)(aTl + ((size_t)(b * 64 + kc * 4 + wk * 2) * 196) * 32);
#pragma unroll
    for (int r = 0; r < 4; r++) {
      int e = htid + 256 * r;
      if (e < 784) {
        int pos = e >> 2, part = e & 3;
        int py = pos / 14, px = pos - py * 14;
        int d = abufbase + part * APL + (py + 1) * 136 + (px + 1) * 8;
        *(uint4*)(sAh + d) = gh[e];
        *(uint4*)(sAl + d) = gl[e];
      }
    }
  }
  bf16x8 b0h[4], b0l[4], b1h[4], b1l[4];
  LOADB(b0h, b0l, 0, wk * 2);
  __syncthreads();

  for (int it = 0; it < 18; it += 2) {
    STEP(it,     b0h, b0l, b1h, b1l);
    STEP(it + 1, b1h, b1l, b0h, b0l);
  }
  // last STEP's tap_==8 __syncthreads doubles as the pre-reduction barrier:
  // all MFMAs and A-LDS reads are done; A buffers are reusable as f32 scratch.

  // wk1 -> LDS (regions: wq0,1 in sAh; wq2,3 in sAl; 28672 B each)
  if (wk == 1) {
    float* rb = (wq < 2 ? (float*)sAh : (float*)sAl) + (wq & 1) * 7168;
#pragma unroll
    for (int mf = 0; mf < 7; mf++)
#pragma unroll
      for (int nf = 0; nf < 4; nf++)
        *(f32x4*)(rb + (mf * 4 + nf) * 256 + lane * 4) = acc[mf][nf];
  }
  __syncthreads();
  if (wk == 0) {
    const float* rb = (wq < 2 ? (const float*)sAh : (const float*)sAl) + (wq & 1) * 7168;
#pragma unroll
    for (int mf = 0; mf < 7; mf++)
#pragma unroll
      for (int nf = 0; nf < 4; nf++) {
        f32x4 v = *(const f32x4*)(rb + (mf * 4 + nf) * 256 + lane * 4);
        acc[mf][nf][0] += v[0]; acc[mf][nf][1] += v[1];
        acc[mf][nf][2] += v[2]; acc[mf][nf][3] += v[3];
      }

    // p1[kc][b][pos196][oc128], coalesced 64B segments
    float* pk = p1 + ((size_t)kc * NB + b) * 196 * 128;
#pragma unroll
    for (int mf = 0; mf < 7; mf++) {
      const int row0 = wm * 112 + mf * 16 + q * 4;
#pragma unroll
      for (int nf = 0; nf < 4; nf++) {
        const int oc = wn * 64 + nf * 16 + ln;
#pragma unroll
        for (int r = 0; r < 4; r++) {
          const int row = row0 + r;
          if (row < 196) pk[(size_t)row * 128 + oc] = acc[mf][nf][r];
        }
      }
    }
  }
}

// finish: sum 16 kc slabs + bias + relu; LDS transpose -> coalesced d1[b][oc][pos] writes
__global__ __launch_bounds__(256)
void conv1_finish_p(const float* __restrict__ p1, const float* __restrict__ bias,
                    float* __restrict__ d1) {
  __shared__ float s[28 * 132];
  const int bid = blockIdx.x;       // 112 = 16 b x 7 pos-tiles(28)
  const int pt = bid % 7, b = bid / 7;
  const int tid = threadIdx.x;
#pragma unroll
  for (int r = 0; r < 4; r++) {
    int u = tid + 256 * r;
    if (u < 896) {
      int pos = u >> 5, oc4 = u & 31;
      const float* base = p1 + ((size_t)(b * 196 + pt * 28 + pos)) * 128 + oc4 * 4;
      float4 sum = ((const float4*)bias)[oc4];
#pragma unroll
      for (int k = 0; k < 16; k++) {
        float4 v = *(const float4*)(base + (size_t)k * NBP);
        sum.x += v.x; sum.y += v.y; sum.z += v.z; sum.w += v.w;
      }
      sum.x = fmaxf(sum.x, 0.f); sum.y = fmaxf(sum.y, 0.f);
      sum.z = fmaxf(sum.z, 0.f); sum.w = fmaxf(sum.w, 0.f);
      *(float4*)(s + pos * 132 + oc4 * 4) = sum;
    }
  }
  __syncthreads();
#pragma unroll
  for (int r = 0; r < 4; r++) {
    int u = tid + 256 * r;
    if (u < 896) {
      int oc = u / 7, f = u - oc * 7;
      float4 v;
      v.x = s[(f * 4 + 0) * 132 + oc];
      v.y = s[(f * 4 + 1) * 132 + oc];
      v.z = s[(f * 4 + 2) * 132 + oc];
      v.w = s[(f * 4 + 3) * 132 + oc];
      *(float4*)(d1 + ((size_t)b * 128 + oc) * 196 + pt * 28 + f * 4) = v;
    }
  }
}

// ---------------- conv2: d1 [16,128,14,14] -> partials, stride2 pad1 ----------------
__global__ void conv2_part(const float* __restrict__ d1, const float* __restrict__ w,
                           float* __restrict__ p2) {
  const int bid = blockIdx.x;
  const int kc = bid & 3, oct = (bid >> 2) & 3, b = bid >> 4;
  const int ic0 = kc * 32, oc0 = oct * 32;
  const int tid = threadIdx.x;
  const int ocl = tid >> 3, rw = tid & 7;

  __shared__ float s_in[32 * 320];
  __shared__ float s_w[32 * 324];

#pragma unroll
  for (int r = 0; r < 32; r++) {
    const int e = tid + 256 * r;
    const int ch = e >> 8, idx = e & 255;
    const int tr = idx >> 4, tc = idx & 15;
    const int iy = tr - 1, ix = tc - 1;
    float v = 0.f;
    if ((unsigned)iy < 14u && (unsigned)ix < 14u)
      v = d1[((size_t)b * 128 + ic0 + ch) * 196 + iy * 14 + ix];
    s_in[ch * 320 + tr * 20 + tc] = v;
  }
#pragma unroll
  for (int r = 0; r < 36; r++) {
    const int e = tid + 256 * r;
    const int oc = e / 288, rem = e - oc * 288;
    const int ch = rem / 9, tap = rem - ch * 9;
    s_w[ch * 324 + tap * 36 + oc] =
        w[(size_t)(oc0 + oc) * 1152 + (size_t)ic0 * 9 + rem];
  }
  __syncthreads();

  if (rw < 7) {
    float acc[7] = {};
    for (int ic = 0; ic < 32; ic++) {
      const float* wrow = s_w + ic * 324 + ocl;
      const float* irow = s_in + ic * 320;
#pragma unroll
      for (int ky = 0; ky < 3; ky++) {
        const float* r = irow + (2 * rw + ky) * 20;
        const float4 f0 = *(const float4*)(r);
        const float4 f1 = *(const float4*)(r + 4);
        const float4 f2 = *(const float4*)(r + 8);
        const float4 f3 = *(const float4*)(r + 12);
        const float ev[8] = {f0.x, f0.z, f1.x, f1.z, f2.x, f2.z, f3.x, f3.z};
        const float od[7] = {f0.y, f0.w, f1.y, f1.w, f2.y, f2.w, f3.y};
        const float w0 = wrow[(ky * 3 + 0) * 36];
        const float w1 = wrow[(ky * 3 + 1) * 36];
        const float w2 = wrow[(ky * 3 + 2) * 36];
#pragma unroll
        for (int x = 0; x < 7; x++)
          acc[x] = fmaf(w0, ev[x], fmaf(w1, od[x], fmaf(w2, ev[x + 1], acc[x])));
      }
    }
    float* po = p2 + (((size_t)kc * NB + b) * 128 + oc0 + ocl) * 49 + rw * 7;
#pragma unroll
    for (int x = 0; x < 7; x++) po[x] = acc[x];
  }
}

__global__ void conv2_finish(const float* __restrict__ p2, const float* __restrict__ bias,
                             float* __restrict__ d2) {
  const int i = blockIdx.x * 256 + threadIdx.x;
  if (i >= NB * 128 * 49) return;
  const int oc = (i / 49) & 127;
  float s = bias[oc];
#pragma unroll
  for (int k = 0; k < 4; k++) s += p2[(size_t)k * (NB * 128 * 49) + i];
  d2[i] = fmaxf(s, 0.f);
}

// ---------------- conv3: d2 [16,128,7,7] -> partials, stride2 pad1 ----------------
__global__ void conv3_part(const float* __restrict__ d2, const float* __restrict__ w,
                           float* __restrict__ p3) {
  const int bid = blockIdx.x;
  const int kc = bid & 1, oct = (bid >> 1) & 7, b = bid >> 4;
  const int ic0 = kc * 64, oc0 = oct * 16;
  const int tid = threadIdx.x;
  const int oc = tid >> 4, p = tid & 15;
  const int y = p >> 2, x = p & 3;

  __shared__ float s_in[64 * 108];
  __shared__ float s_w[64 * 144];

#pragma unroll
  for (int r = 0; r < 21; r++) {
    const int e = tid + 256 * r;
    if (e < 64 * 81) {
      const int ch = e / 81, idx = e - ch * 81;
      const int tr = idx / 9, tc = idx - tr * 9;
      const int iy = tr - 1, ix = tc - 1;
      float v = 0.f;
      if ((unsigned)iy < 7u && (unsigned)ix < 7u)
        v = d2[((size_t)b * 128 + ic0 + ch) * 49 + iy * 7 + ix];
      s_in[ch * 108 + tr * 12 + tc] = v;
    }
  }
#pragma unroll
  for (int r = 0; r < 36; r++) {
    const int e = tid + 256 * r;
    const int o = e / 576, rem = e - o * 576;
    const int ch = rem / 9, tap = rem - ch * 9;
    s_w[ch * 144 + tap * 16 + o] =
        w[(size_t)(oc0 + o) * 1152 + (size_t)ic0 * 9 + rem];
  }
  __syncthreads();

  float acc = 0.f;
  for (int ic = 0; ic < 64; ic++) {
    const float* wrow = s_w + ic * 144 + oc;
    const float* irow = s_in + ic * 108 + 2 * y * 12 + 2 * x;
#pragma unroll
    for (int ky = 0; ky < 3; ky++)
#pragma unroll
      for (int kx = 0; kx < 3; kx++)
        acc = fmaf(wrow[(ky * 3 + kx) * 16], irow[ky * 12 + kx], acc);
  }
  p3[(((size_t)kc * NB + b) * 128 + oc0 + oc) * 16 + p] = acc;
}

// ---------------- fused tidy(1x1 convs) + NMS; d3 folded in from p3 ----------------
__global__ __launch_bounds__(256, 1)
void score_nms(const float* __restrict__ d1, const float* __restrict__ d2,
               const float* __restrict__ p3, const float* __restrict__ bd3,
               const float* __restrict__ w1, const float* __restrict__ b1,
               const float* __restrict__ w2, const float* __restrict__ b2,
               const float* __restrict__ w3, const float* __restrict__ b3,
               const int* __restrict__ anchors, float* __restrict__ score,
               float* __restrict__ out_idx, float* __restrict__ out_prob,
               float* __restrict__ sel) {
  __shared__ float s_in[32 * 200];     // t1 chunks; reused linearly for d2 (6272) / d3 (2048)
  __shared__ float s_w[21 * 128];      // w1(0..5), w2(6..11), w3(12..20)
  __shared__ float s_b[21];
  __shared__ float s_sc[NA];
  __shared__ float s_bx[NA * 4];
  __shared__ float r_s[256];
  __shared__ int r_i[256];
  const int b = blockIdx.x, tid = threadIdx.x;

  for (int i = tid; i < 768; i += 256) s_w[i] = w1[i];
  for (int i = tid; i < 768; i += 256) s_w[768 + i] = w2[i];
  for (int i = tid; i < 1152; i += 256) s_w[1536 + i] = w3[i];
  if (tid < 21) s_b[tid] = (tid < 6) ? b1[tid] : (tid < 12) ? b2[tid - 6] : b3[tid - 12];
  for (int i = tid; i < NA; i += 256) {
    s_bx[i * 4 + 0] = (float)anchors[i * 4 + 0];
    s_bx[i * 4 + 1] = (float)anchors[i * 4 + 1];
    s_bx[i * 4 + 2] = (float)anchors[i * 4 + 2];
    s_bx[i * 4 + 3] = (float)anchors[i * 4 + 3];
  }

  // ---- t1: 6 oc x 196 pos = 1176 scores, d1 staged in 4 chunks of 32 ic ----
  float acc[5] = {0.f, 0.f, 0.f, 0.f, 0.f};
  for (int chunk = 0; chunk < 4; chunk++) {
    __syncthreads();
    const float* src = d1 + ((size_t)b * 128 + chunk * 32) * 196;
#pragma unroll
    for (int r = 0; r < 7; r++) {
      int e = tid + 256 * r;
      if (e < 1568) {
        int ic = e / 49, f = e - ic * 49;
        *(float4*)(s_in + ic * 200 + f * 4) = ((const float4*)(src + (size_t)ic * 196))[f];
      }
    }
    __syncthreads();
#pragma unroll
    for (int k = 0; k < 5; k++) {
      int j = tid + 256 * k;
      if (j < 1176) {
        int oc = j / 196, p = j - oc * 196;
        const float* wr = s_w + oc * 128 + chunk * 32;
        float s = acc[k];
#pragma unroll
        for (int ic = 0; ic < 32; ic++) s = fmaf(wr[ic], s_in[ic * 200 + p], s);
        acc[k] = s;
      }
    }
  }
#pragma unroll
  for (int k = 0; k < 5; k++) {
    int j = tid + 256 * k;
    if (j < 1176) {
      int oc = j / 196;
      float s = acc[k] + s_b[oc];
      s_sc[j] = s;
      score[b * NA + j] = s;
    }
  }

  // ---- t2: 6 oc x 49 = 294 scores, d2[b] staged fully (linear) ----
  __syncthreads();
  {
    const float* src = d2 + (size_t)b * 6272;
#pragma unroll
    for (int r = 0; r < 7; r++) {
      int e = tid + 256 * r;
      if (e < 1568) *(float4*)(s_in + e * 4) = ((const float4*)src)[e];
    }
  }
  __syncthreads();
#pragma unroll
  for (int k = 0; k < 2; k++) {
    int jj = tid + 256 * k;
    if (jj < 294) {
      int oc = jj / 49, p = jj - oc * 49;
      const float* wr = s_w + 768 + oc * 128;
      float s = s_b[6 + oc];
#pragma unroll 8
      for (int ic = 0; ic < 128; ic++) s = fmaf(wr[ic], s_in[ic * 49 + p], s);
      s_sc[1176 + jj] = s;
      score[b * NA + 1176 + jj] = s;
    }
  }

  // ---- t3: 9 oc x 16 = 144 scores; d3 = relu(p3[0]+p3[1]+bd3) computed inline ----
  __syncthreads();
  {
    const float4* s0 = (const float4*)(p3 + (size_t)b * 2048);
    const float4* s1 = (const float4*)(p3 + 32768 + (size_t)b * 2048);
#pragma unroll
    for (int r = 0; r < 2; r++) {
      int e = tid + 256 * r;
      if (e < 512) {
        float4 a = s0[e], c = s1[e];
        float bb = bd3[e >> 2];
        float4 v;
        v.x = fmaxf(a.x + c.x + bb, 0.f);
        v.y = fmaxf(a.y + c.y + bb, 0.f);
        v.z = fmaxf(a.z + c.z + bb, 0.f);
        v.w = fmaxf(a.w + c.w + bb, 0.f);
        *(float4*)(s_in + e * 4) = v;
      }
    }
  }
  __syncthreads();
  if (tid < 144) {
    int oc = tid >> 4, p = tid & 15;
    const float* wr = s_w + 1536 + oc * 128;
    float s = s_b[12 + oc];
#pragma unroll 8
    for (int ic = 0; ic < 128; ic++) s = fmaf(wr[ic], s_in[ic * 16 + p], s);
    s_sc[1470 + tid] = s;
    score[b * NA + 1470 + tid] = s;
  }
  __syncthreads();

  // ---- NMS: TOPN=4, IoU>0.25 suppress ----
  for (int t = 0; t < 4; t++) {
    float bs = -__builtin_inff();
    int bi = NA;
    for (int i = tid; i < NA; i += 256) {
      float s = s_sc[i];
      if (s > bs || (s == bs && i < bi)) { bs = s; bi = i; }
    }
    r_s[tid] = bs; r_i[tid] = bi;
    __syncthreads();
    for (int off = 128; off > 0; off >>= 1) {
      if (tid < off) {
        float s2 = r_s[tid + off]; int i2 = r_i[tid + off];
        if (s2 > r_s[tid] || (s2 == r_s[tid] && i2 < r_i[tid])) { r_s[tid] = s2; r_i[tid] = i2; }
      }
      __syncthreads();
    }
    const int idx = r_i[0];
    const float by0 = s_bx[idx * 4 + 0], bx0 = s_bx[idx * 4 + 1];
    const float by1 = s_bx[idx * 4 + 2], bx1 = s_bx[idx * 4 + 3];
    if (tid == 0) {
      out_idx[b * 4 + t] = (float)idx;
      out_prob[b * 4 + t] = s_sc[idx];
      sel[(b * 4 + t) * 4 + 0] = by0;
      sel[(b * 4 + t) * 4 + 1] = bx0;
      sel[(b * 4 + t) * 4 + 2] = by1;
      sel[(b * 4 + t) * 4 + 3] = bx1;
    }
    __syncthreads();
    const float a = (by1 - by0) * (bx1 - bx0);
    for (int i = tid; i < NA; i += 256) {
      float cy0 = s_bx[i * 4 + 0], cx0 = s_bx[i * 4 + 1];
      float cy1 = s_bx[i * 4 + 2], cx1 = s_bx[i * 4 + 3];
      float yy0 = fmaxf(by0, cy0), xx0 = fmaxf(bx0, cx0);
      float yy1 = fminf(by1, cy1), xx1 = fminf(bx1, cx1);
      float inter = fmaxf(yy1 - yy0, 0.f) * fmaxf(xx1 - xx0, 0.f);
      float ar = (cy1 - cy0) * (cx1 - cx0);
      float iou = inter / (a + ar - inter);
      if (iou > 0.25f) s_sc[i] = -__builtin_inff();
    }
    __syncthreads();
  }
}

// ---------------- crop+bilinear resize to [16,4,3,224,224], 4 px/thread ----------------
__global__ void crop_kernel(const float* __restrict__ x, const float* __restrict__ sel,
                            float* __restrict__ out) {
  int i4 = blockIdx.x * 256 + threadIdx.x;
  const int total4 = NB * 4 * 3 * 224 * 56;
  if (i4 >= total4) return;
  int px0 = (i4 % 56) * 4;
  int t = i4 / 56;
  int py = t % 224; t /= 224;
  int ch = t % 3;  t /= 3;
  int n  = t % 4;
  int b  = t / 4;

  const float* bx = sel + (b * 4 + n) * 4;
  const float y0 = bx[0], x0 = bx[1], y1 = bx[2], x1 = bx[3];

  float ty = (float)py / 223.0f;
  float cy = y0 + (y1 - 1.0f - y0) * ty;
  float cyf = floorf(cy);
  int ylo = (int)cyf; ylo = ylo < 0 ? 0 : (ylo > 895 ? 895 : ylo);
  int yhi = ylo + 1 > 895 ? 895 : ylo + 1;
  float wy = cy - cyf;

  const float* img = x + ((size_t)b * 3 + ch) * 448 * 448;
  auto g = [&](int yy, int xx) -> float {
    yy -= 224; xx -= 224;
    if ((unsigned)yy < 448u && (unsigned)xx < 448u)
      return img[(size_t)yy * 448 + xx];
    return 0.f;
  };

  float4 res;
  float* rp = &res.x;
#pragma unroll
  for (int k = 0; k < 4; k++) {
    float tx = (float)(px0 + k) / 223.0f;
    float cx = x0 + (x1 - 1.0f - x0) * tx;
    float cxf = floorf(cx);
    int xlo = (int)cxf; xlo = xlo < 0 ? 0 : (xlo > 895 ? 895 : xlo);
    int xhi = xlo + 1 > 895 ? 895 : xlo + 1;
    float wx = cx - cxf;
    float v00 = g(ylo, xlo), v01 = g(ylo, xhi);
    float v10 = g(yhi, xlo), v11 = g(yhi, xhi);
    rp[k] = (1.f - wy) * ((1.f - wx) * v00 + wx * v01) +
            wy * ((1.f - wx) * v10 + wx * v11);
  }
  *(float4*)(out + (size_t)i4 * 4) = res;
}

extern "C" void kernel_launch(void* const* d_in, const int* in_sizes, int n_in,
                              void* d_out, int out_size, void* d_ws, size_t ws_size,
                              hipStream_t stream) {
  const float* x    = (const float*)d_in[0];
  const float* rpn  = (const float*)d_in[1];
  const int*   anc  = (const int*)d_in[2];
  const float* w_d1 = (const float*)d_in[3];
  const float* b_d1 = (const float*)d_in[4];
  const float* w_d2 = (const float*)d_in[5];
  const float* b_d2 = (const float*)d_in[6];
  const float* w_d3 = (const float*)d_in[7];
  const float* b_d3 = (const float*)d_in[8];
  const float* w_t1 = (const float*)d_in[9];
  const float* b_t1 = (const float*)d_in[10];
  const float* w_t2 = (const float*)d_in[11];
  const float* b_t2 = (const float*)d_in[12];
  const float* w_t3 = (const float*)d_in[13];
  const float* b_t3 = (const float*)d_in[14];

  float* out = (float*)d_out;
  float* ws = (float*)d_ws;

  float* d1  = ws;                        // 401408
  float* d2  = d1 + 401408;               // 100352
  float* d3  = d2 + 100352;               // 32768 (unused slot, kept for layout stability)
  float* sel = d3 + 32768;                // 256
  float* p2  = sel + 256;                 // 401408
  float* p3  = p2 + 401408;               // 65536
  unsigned short* wTh = (unsigned short*)(p3 + 65536);   // 2,359,296 ush
  unsigned short* wTl = wTh + 2359296;                   // 2,359,296 ush
  unsigned short* aTh = wTl + 2359296;                   // 6,422,528 ush
  unsigned short* aTl = aTh + 6422528;                   // 6,422,528 ush
  // total ws need: 39,134,208 B (identical to verified layout)

  float* score    = out;                  // 25824
  float* out_idx  = out + 25824;          // 64
  float* out_prob = out + 25888;          // 64
  float* parts    = out + 25952;          // 9,633,792 (final crop output)
  float* p1       = parts;                // 6,422,528 floats scratch; crop overwrites after

  prep<<<dim3(10240), dim3(256), 0, stream>>>(w_d1, rpn, wTh, wTl, aTh, aTl);
  conv1_mfma<<<dim3(256), dim3(512), 0, stream>>>(aTh, aTl, wTh, wTl, p1);
  conv1_finish_p<<<dim3(112), dim3(256), 0, stream>>>(p1, b_d1, d1);
  conv2_part<<<dim3(256), dim3(256), 0, stream>>>(d1, w_d2, p2);
  conv2_finish<<<dim3(392), dim3(256), 0, stream>>>(p2, b_d2, d2);
  conv3_part<<<dim3(256), dim3(256), 0, stream>>>(d2, w_d3, p3);
  score_nms<<<dim3(16), dim3(256), 0, stream>>>(d1, d2, p3, b_d3, w_t1, b_t1, w_t2, b_t2,
                                                w_t3, b_t3, anc, score, out_idx, out_prob, sel);
  crop_kernel<<<dim3(9408), dim3(256), 0, stream>>>(x, sel, parts);
}

// Round 4
// 275.892 us; speedup vs baseline: 1.0220x; 1.0220x over previous
//
#include <hip/hip_runtime.h>
#include <hip/hip_bf16.h>

#define NB 16
#define NA 1614
#define NBP (NB * 196 * 128)   // p1 slab stride = 401408

typedef __bf16 bf16x8 __attribute__((ext_vector_type(8)));
typedef float f32x4 __attribute__((ext_vector_type(4)));

__device__ __forceinline__ unsigned short f2bf(float v) {
  unsigned u = __float_as_uint(v);
  unsigned r = (u + 0x7FFFu + ((u >> 16) & 1u)) >> 16;
  return (unsigned short)r;
}
__device__ __forceinline__ float bf2f(unsigned short s) {
  return __uint_as_float(((unsigned)s) << 16);
}

// ---------------- prep (fused): blocks [0,1024) transpose+split rpn -> aT; rest -> wT ------
// aT layout: [chunk = b*64 + ic32grp][pos196][ic32] hi/lo, written fully coalesced (pos-major).
// wT layout: [kc16][tap9][ks4][oc128][icq4][8] hi/lo -> conv1 B-fragment reads are
// fully coalesced global loads (no B LDS staging needed).
__global__ __launch_bounds__(256)
void prep(const float* __restrict__ w, const float* __restrict__ in,
          unsigned short* __restrict__ wTh, unsigned short* __restrict__ wTl,
          unsigned short* __restrict__ aTh, unsigned short* __restrict__ aTl) {
  __shared__ float s[32 * 201];
  const int bid = blockIdx.x;
  if (bid < 1024) {
    const int chunk = bid & 63, b = bid >> 6;
    const float* src = in + ((size_t)b * 2048 + chunk * 32) * 196;
#pragma unroll
    for (int r = 0; r < 7; r++) {
      int e = threadIdx.x + 256 * r;
      if (e < 1568) {
        int ic = e / 49, f = e - ic * 49;
        float4 v = ((const float4*)(src + (size_t)ic * 196))[f];
        float* d = s + ic * 201 + f * 4;
        d[0] = v.x; d[1] = v.y; d[2] = v.z; d[3] = v.w;
      }
    }
    __syncthreads();
    unsigned short* oh = aTh + (size_t)bid * (196 * 32);
    unsigned short* ol = aTl + (size_t)bid * (196 * 32);
#pragma unroll
    for (int r = 0; r < 4; r++) {
      int e = threadIdx.x + 256 * r;   // uint4 units; e = pos*4 + part -> contiguous writes
      if (e < 784) {
        int pos = e >> 2, part = e & 3;
        unsigned short hv[8], lv[8];
#pragma unroll
        for (int j = 0; j < 8; j++) {
          float v = s[(part * 8 + j) * 201 + pos];
          unsigned short h = f2bf(v);
          hv[j] = h;
          lv[j] = f2bf(v - bf2f(h));
        }
        ((uint4*)oh)[e] = *(uint4*)hv;
        ((uint4*)ol)[e] = *(uint4*)lv;
      }
    }
  } else {
    int e = (bid - 1024) * 256 + threadIdx.x;
    if (e < 9 * 128 * 2048) {
      int tap = e / (128 * 2048);
      int rem = e - tap * (128 * 2048);
      int oc = rem >> 11, ic = rem & 2047;
      // decompose ic = kc*128 + ks*32 + icq*8 + j
      int kcp = ic >> 7, ks = (ic >> 5) & 3, icq = (ic >> 3) & 3, j = ic & 7;
      size_t g2 = ((size_t)(kcp * 36 + tap * 4 + ks) << 12) + oc * 32 + icq * 8 + j;
      float v = w[((size_t)oc * 2048 + ic) * 9 + tap];
      unsigned short h = f2bf(v);
      wTh[g2] = h;
      wTl[g2] = f2bf(v - bf2f(h));
    }
  }
}

// ---------------- conv1 MFMA: implicit GEMM, split-bf16, M-split blocks ----------------
// grid 512 = kc(16, low bits -> B slices XCD-L2-local) x b(16) x mh(2).
// Block = 256 thr = 4 waves (wn0..3), M112 x N128; wave tile M112 x N32 (mf7 x nf2).
// 2 INDEPENDENT blocks/CU (43.5KB LDS each, ~180 VGPR/wave -> no spill at the
// 256-VGPR/2-wave cap): one block's LDS/VMEM waits overlap the other's MFMA issue,
// with DECOUPLED barrier schedules (round-3 post-mortem: intra-block K-split spilled
// [WRITE_SIZE +19MB scratch] and coupled both halves through one barrier).
// Per-CU totals vs round 2: MFMA same, B bytes same (twin block hits same L2 lines),
// A-LDS reads 2x (112KB/iter, under the 256B/cy ceiling, hidden by overlap).
//  - B fragments from global (L2-resident), register double-buffered.
//  - A half-tile (10 padded rows) double-buffered in LDS; next-ks staged at taps 2..4.
//  - Epilogue: plain register->p1 store of this block's disjoint row range.
#define APL 1360          // ush per icq plane (10 rows x 136)
#define ABUF (4 * APL)    // ush per A buffer (5440)

#define LOADB(H, L, T, K)                                                     \
  {                                                                           \
    const size_t o_ = ((size_t)(kc * 36 + (T) * 4 + (K)) << 12) + bln;        \
    const unsigned short* ph_ = wTh + o_;                                     \
    const unsigned short* pq_ = wTl + o_;                                     \
    H[0] = *(const bf16x8*)(ph_);                                             \
    H[1] = *(const bf16x8*)(ph_ + 512);                                       \
    L[0] = *(const bf16x8*)(pq_);                                             \
    L[1] = *(const bf16x8*)(pq_ + 512);                                       \
  }

#define STEP(IT, BUH, BUL, BNH, BNL)                                          \
  {                                                                           \
    const int it_ = (IT);                                                     \
    const int ks_ = it_ / 9, tap_ = it_ - ks_ * 9;                            \
    { /* prefetch next iter's B into the alternate register set */            \
      const int ni_ = (it_ < 35) ? it_ + 1 : 35;                              \
      const int nk_ = ni_ / 9, nt_ = ni_ - nk_ * 9;                           \
      LOADB(BNH, BNL, nt_, nk_);                                              \
    }                                                                         \
    if (ks_ < 3) { /* stage next ks: load taps 2..3, write taps 3..4 */       \
      if (tap_ == 3 || tap_ == 4) {                                           \
        int e_ = tid + 256 * (tap_ - 3);                                      \
        if (e_ < ne) {                                                        \
          int u_ = pos04 + e_;                                                \
          int pos_ = u_ >> 2, part_ = u_ & 3;                                 \
          int py_ = pos_ / 14, px_ = pos_ - py_ * 14;                         \
          int d_ = (((ks_ + 1) & 1) ? ABUF : 0) + part_ * APL                 \
                   + (py_ + 1 - rowoff) * 136 + (px_ + 1) * 8;                \
          *(uint4*)(sAh + d_) = sgh;                                          \
          *(uint4*)(sAl + d_) = sgl;                                          \
        }                                                                     \
      }                                                                       \
      if (tap_ == 2 || tap_ == 3) {                                           \
        const uint4* gh_ = (const uint4*)(aTh + ((size_t)(b * 64 + kc * 4 + ks_ + 1) * 196) * 32); \
        const uint4* gl_ = (const uint4*)(aTl + ((size_t)(b * 64 + kc * 4 + ks_ + 1) * 196) * 32); \
        int e_ = tid + 256 * (tap_ - 2);                                      \
        if (e_ < ne) { sgh = gh_[pos04 + e_]; sgl = gl_[pos04 + e_]; }        \
      }                                                                       \
    }                                                                         \
    const int t8_ = (tap_ / 3) * 136 + (tap_ - (tap_ / 3) * 3) * 8;           \
    const unsigned short* pah_ = sAh + (ks_ & 1) * ABUF + qoff + t8_;         \
    const unsigned short* pal_ = sAl + (ks_ & 1) * ABUF + qoff + t8_;         \
    bf16x8 afh[7], afl[7];                                                    \
    _Pragma("unroll") for (int mf = 0; mf < 7; mf++) {                        \
      afh[mf] = *(const bf16x8*)(pah_ + abase[mf]);                           \
      afl[mf] = *(const bf16x8*)(pal_ + abase[mf]);                           \
    }                                                                         \
    _Pragma("unroll") for (int mf = 0; mf < 7; mf++)                          \
      _Pragma("unroll") for (int nf = 0; nf < 2; nf++)                        \
        acc[mf][nf] = __builtin_amdgcn_mfma_f32_16x16x32_bf16(afh[mf], BUH[nf], acc[mf][nf], 0, 0, 0); \
    _Pragma("unroll") for (int mf = 0; mf < 7; mf++)                          \
      _Pragma("unroll") for (int nf = 0; nf < 2; nf++)                        \
        acc[mf][nf] = __builtin_amdgcn_mfma_f32_16x16x32_bf16(afl[mf], BUH[nf], acc[mf][nf], 0, 0, 0); \
    _Pragma("unroll") for (int mf = 0; mf < 7; mf++)                          \
      _Pragma("unroll") for (int nf = 0; nf < 2; nf++)                        \
        acc[mf][nf] = __builtin_amdgcn_mfma_f32_16x16x32_bf16(afh[mf], BUL[nf], acc[mf][nf], 0, 0, 0); \
    if (tap_ == 8) __syncthreads();                                           \
  }

__global__ __launch_bounds__(256, 2)
void conv1_mfma(const unsigned short* __restrict__ aTh, const unsigned short* __restrict__ aTl,
                const unsigned short* __restrict__ wTh, const unsigned short* __restrict__ wTl,
                float* __restrict__ p1) {
  const int bid = blockIdx.x;
  const int kc = bid & 15;
  const int b  = (bid >> 4) & 15;
  const int mh = bid >> 8;
  const int tid = threadIdx.x;
  const int wid = tid >> 6, lane = tid & 63;
  const int wn = wid;
  const int q = lane >> 4, ln = lane & 15;

  __shared__ unsigned short sAh[2 * ABUF];
  __shared__ unsigned short sAl[2 * ABUF];

  // this block's M-half geometry
  const int rowoff = 6 * mh;                 // padded-row p stored at local row p-rowoff
  const int pos0 = mh ? 98 : 0;              // staged input pos range [pos0, pos0+npos)
  const int ne   = mh ? 392 : 504;           // npos*4 uint4 elements
  const int pos04 = pos0 * 4;

  // zero both A buffers once: padded borders stay zero (stages overwrite interior only)
  for (int e = tid; e < 2 * ABUF / 2; e += 256) {   // u32 units: 2*ABUF ush = 5440 u32
    ((unsigned int*)sAh)[e] = 0u;
    ((unsigned int*)sAl)[e] = 0u;
  }

  int abase[7];
#pragma unroll
  for (int mf = 0; mf < 7; mf++) {
    int row = mh * 112 + mf * 16 + ln;
    int y = row / 14, x = row - y * 14;
    abase[mf] = (row < 196) ? ((y - rowoff) * 136 + x * 8) : 0;
  }
  const int qoff = q * APL;
  const int bln = (wn * 32 + ln) * 32 + q * 8;   // per-lane B offset (oc-major coalesced)

  f32x4 acc[7][2];
#pragma unroll
  for (int mf = 0; mf < 7; mf++)
#pragma unroll
    for (int nf = 0; nf < 2; nf++) acc[mf][nf] = (f32x4){0.f, 0.f, 0.f, 0.f};

  uint4 sgh = {}, sgl = {};   // in-flight A staging registers

  __syncthreads();   // zero-init complete before interior staging

  // prologue: stage ks=0 rows for this M-half into buffer 0; load iter 0's B
  {
    const uint4* gh = (const uint4*)(aTh + ((size_t)(b * 64 + kc * 4) * 196) * 32);
    const uint4* gl = (const uint4*)(aTl + ((size_t)(b * 64 + kc * 4) * 196) * 32);
#pragma unroll
    for (int r = 0; r < 2; r++) {
      int e = tid + 256 * r;
      if (e < ne) {
        int u = pos04 + e;
        int pos = u >> 2, part = u & 3;
        int py = pos / 14, px = pos - py * 14;
        int d = part * APL + (py + 1 - rowoff) * 136 + (px + 1) * 8;
        *(uint4*)(sAh + d) = gh[u];
        *(uint4*)(sAl + d) = gl[u];
      }
    }
  }
  bf16x8 b0h[2], b0l[2], b1h[2], b1l[2];
  LOADB(b0h, b0l, 0, 0);
  __syncthreads();

  for (int it = 0; it < 36; it += 2) {
    STEP(it,     b0h, b0l, b1h, b1l);
    STEP(it + 1, b1h, b1l, b0h, b0l);
  }

  // p1[kc][b][pos196][oc128]; this block writes rows [mh*112, mh*112+112) ∩ [0,196)
  float* pk = p1 + ((size_t)kc * NB + b) * 196 * 128;
#pragma unroll
  for (int mf = 0; mf < 7; mf++) {
    const int row0 = mh * 112 + mf * 16 + q * 4;
#pragma unroll
    for (int nf = 0; nf < 2; nf++) {
      const int oc = wn * 32 + nf * 16 + ln;
#pragma unroll
      for (int r = 0; r < 4; r++) {
        const int row = row0 + r;
        if (row < 196) pk[(size_t)row * 128 + oc] = acc[mf][nf][r];
      }
    }
  }
}

// finish: sum 16 kc slabs + bias + relu; LDS transpose -> coalesced d1[b][oc][pos] writes
__global__ __launch_bounds__(256)
void conv1_finish_p(const float* __restrict__ p1, const float* __restrict__ bias,
                    float* __restrict__ d1) {
  __shared__ float s[28 * 132];
  const int bid = blockIdx.x;       // 112 = 16 b x 7 pos-tiles(28)
  const int pt = bid % 7, b = bid / 7;
  const int tid = threadIdx.x;
#pragma unroll
  for (int r = 0; r < 4; r++) {
    int u = tid + 256 * r;
    if (u < 896) {
      int pos = u >> 5, oc4 = u & 31;
      const float* base = p1 + ((size_t)(b * 196 + pt * 28 + pos)) * 128 + oc4 * 4;
      float4 sum = ((const float4*)bias)[oc4];
#pragma unroll
      for (int k = 0; k < 16; k++) {
        float4 v = *(const float4*)(base + (size_t)k * NBP);
        sum.x += v.x; sum.y += v.y; sum.z += v.z; sum.w += v.w;
      }
      sum.x = fmaxf(sum.x, 0.f); sum.y = fmaxf(sum.y, 0.f);
      sum.z = fmaxf(sum.z, 0.f); sum.w = fmaxf(sum.w, 0.f);
      *(float4*)(s + pos * 132 + oc4 * 4) = sum;
    }
  }
  __syncthreads();
#pragma unroll
  for (int r = 0; r < 4; r++) {
    int u = tid + 256 * r;
    if (u < 896) {
      int oc = u / 7, f = u - oc * 7;
      float4 v;
      v.x = s[(f * 4 + 0) * 132 + oc];
      v.y = s[(f * 4 + 1) * 132 + oc];
      v.z = s[(f * 4 + 2) * 132 + oc];
      v.w = s[(f * 4 + 3) * 132 + oc];
      *(float4*)(d1 + ((size_t)b * 128 + oc) * 196 + pt * 28 + f * 4) = v;
    }
  }
}

// ---------------- conv2: d1 [16,128,14,14] -> partials, stride2 pad1 ----------------
__global__ void conv2_part(const float* __restrict__ d1, const float* __restrict__ w,
                           float* __restrict__ p2) {
  const int bid = blockIdx.x;
  const int kc = bid & 3, oct = (bid >> 2) & 3, b = bid >> 4;
  const int ic0 = kc * 32, oc0 = oct * 32;
  const int tid = threadIdx.x;
  const int ocl = tid >> 3, rw = tid & 7;

  __shared__ float s_in[32 * 320];
  __shared__ float s_w[32 * 324];

#pragma unroll
  for (int r = 0; r < 32; r++) {
    const int e = tid + 256 * r;
    const int ch = e >> 8, idx = e & 255;
    const int tr = idx >> 4, tc = idx & 15;
    const int iy = tr - 1, ix = tc - 1;
    float v = 0.f;
    if ((unsigned)iy < 14u && (unsigned)ix < 14u)
      v = d1[((size_t)b * 128 + ic0 + ch) * 196 + iy * 14 + ix];
    s_in[ch * 320 + tr * 20 + tc] = v;
  }
#pragma unroll
  for (int r = 0; r < 36; r++) {
    const int e = tid + 256 * r;
    const int oc = e / 288, rem = e - oc * 288;
    const int ch = rem / 9, tap = rem - ch * 9;
    s_w[ch * 324 + tap * 36 + oc] =
        w[(size_t)(oc0 + oc) * 1152 + (size_t)ic0 * 9 + rem];
  }
  __syncthreads();

  if (rw < 7) {
    float acc[7] = {};
    for (int ic = 0; ic < 32; ic++) {
      const float* wrow = s_w + ic * 324 + ocl;
      const float* irow = s_in + ic * 320;
#pragma unroll
      for (int ky = 0; ky < 3; ky++) {
        const float* r = irow + (2 * rw + ky) * 20;
        const float4 f0 = *(const float4*)(r);
        const float4 f1 = *(const float4*)(r + 4);
        const float4 f2 = *(const float4*)(r + 8);
        const float4 f3 = *(const float4*)(r + 12);
        const float ev[8] = {f0.x, f0.z, f1.x, f1.z, f2.x, f2.z, f3.x, f3.z};
        const float od[7] = {f0.y, f0.w, f1.y, f1.w, f2.y, f2.w, f3.y};
        const float w0 = wrow[(ky * 3 + 0) * 36];
        const float w1 = wrow[(ky * 3 + 1) * 36];
        const float w2 = wrow[(ky * 3 + 2) * 36];
#pragma unroll
        for (int x = 0; x < 7; x++)
          acc[x] = fmaf(w0, ev[x], fmaf(w1, od[x], fmaf(w2, ev[x + 1], acc[x])));
      }
    }
    float* po = p2 + (((size_t)kc * NB + b) * 128 + oc0 + ocl) * 49 + rw * 7;
#pragma unroll
    for (int x = 0; x < 7; x++) po[x] = acc[x];
  }
}

__global__ void conv2_finish(const float* __restrict__ p2, const float* __restrict__ bias,
                             float* __restrict__ d2) {
  const int i = blockIdx.x * 256 + threadIdx.x;
  if (i >= NB * 128 * 49) return;
  const int oc = (i / 49) & 127;
  float s = bias[oc];
#pragma unroll
  for (int k = 0; k < 4; k++) s += p2[(size_t)k * (NB * 128 * 49) + i];
  d2[i] = fmaxf(s, 0.f);
}

// ---------------- conv3: d2 [16,128,7,7] -> partials, stride2 pad1 ----------------
__global__ void conv3_part(const float* __restrict__ d2, const float* __restrict__ w,
                           float* __restrict__ p3) {
  const int bid = blockIdx.x;
  const int kc = bid & 1, oct = (bid >> 1) & 7, b = bid >> 4;
  const int ic0 = kc * 64, oc0 = oct * 16;
  const int tid = threadIdx.x;
  const int oc = tid >> 4, p = tid & 15;
  const int y = p >> 2, x = p & 3;

  __shared__ float s_in[64 * 108];
  __shared__ float s_w[64 * 144];

#pragma unroll
  for (int r = 0; r < 21; r++) {
    const int e = tid + 256 * r;
    if (e < 64 * 81) {
      const int ch = e / 81, idx = e - ch * 81;
      const int tr = idx / 9, tc = idx - tr * 9;
      const int iy = tr - 1, ix = tc - 1;
      float v = 0.f;
      if ((unsigned)iy < 7u && (unsigned)ix < 7u)
        v = d2[((size_t)b * 128 + ic0 + ch) * 49 + iy * 7 + ix];
      s_in[ch * 108 + tr * 12 + tc] = v;
    }
  }
#pragma unroll
  for (int r = 0; r < 36; r++) {
    const int e = tid + 256 * r;
    const int o = e / 576, rem = e - o * 576;
    const int ch = rem / 9, tap = rem - ch * 9;
    s_w[ch * 144 + tap * 16 + o] =
        w[(size_t)(oc0 + o) * 1152 + (size_t)ic0 * 9 + rem];
  }
  __syncthreads();

  float acc = 0.f;
  for (int ic = 0; ic < 64; ic++) {
    const float* wrow = s_w + ic * 144 + oc;
    const float* irow = s_in + ic * 108 + 2 * y * 12 + 2 * x;
#pragma unroll
    for (int ky = 0; ky < 3; ky++)
#pragma unroll
      for (int kx = 0; kx < 3; kx++)
        acc = fmaf(wrow[(ky * 3 + kx) * 16], irow[ky * 12 + kx], acc);
  }
  p3[(((size_t)kc * NB + b) * 128 + oc0 + oc) * 16 + p] = acc;
}

// ---------------- fused tidy(1x1 convs) + NMS; d3 folded in from p3 ----------------
__global__ __launch_bounds__(256, 1)
void score_nms(const float* __restrict__ d1, const float* __restrict__ d2,
               const float* __restrict__ p3, const float* __restrict__ bd3,
               const float* __restrict__ w1, const float* __restrict__ b1,
               const float* __restrict__ w2, const float* __restrict__ b2,
               const float* __restrict__ w3, const float* __restrict__ b3,
               const int* __restrict__ anchors, float* __restrict__ score,
               float* __restrict__ out_idx, float* __restrict__ out_prob,
               float* __restrict__ sel) {
  __shared__ float s_in[32 * 200];     // t1 chunks; reused linearly for d2 (6272) / d3 (2048)
  __shared__ float s_w[21 * 128];      // w1(0..5), w2(6..11), w3(12..20)
  __shared__ float s_b[21];
  __shared__ float s_sc[NA];
  __shared__ float s_bx[NA * 4];
  __shared__ float r_s[256];
  __shared__ int r_i[256];
  const int b = blockIdx.x, tid = threadIdx.x;

  for (int i = tid; i < 768; i += 256) s_w[i] = w1[i];
  for (int i = tid; i < 768; i += 256) s_w[768 + i] = w2[i];
  for (int i = tid; i < 1152; i += 256) s_w[1536 + i] = w3[i];
  if (tid < 21) s_b[tid] = (tid < 6) ? b1[tid] : (tid < 12) ? b2[tid - 6] : b3[tid - 12];
  for (int i = tid; i < NA; i += 256) {
    s_bx[i * 4 + 0] = (float)anchors[i * 4 + 0];
    s_bx[i * 4 + 1] = (float)anchors[i * 4 + 1];
    s_bx[i * 4 + 2] = (float)anchors[i * 4 + 2];
    s_bx[i * 4 + 3] = (float)anchors[i * 4 + 3];
  }

  // ---- t1: 6 oc x 196 pos = 1176 scores, d1 staged in 4 chunks of 32 ic ----
  float acc[5] = {0.f, 0.f, 0.f, 0.f, 0.f};
  for (int chunk = 0; chunk < 4; chunk++) {
    __syncthreads();
    const float* src = d1 + ((size_t)b * 128 + chunk * 32) * 196;
#pragma unroll
    for (int r = 0; r < 7; r++) {
      int e = tid + 256 * r;
      if (e < 1568) {
        int ic = e / 49, f = e - ic * 49;
        *(float4*)(s_in + ic * 200 + f * 4) = ((const float4*)(src + (size_t)ic * 196))[f];
      }
    }
    __syncthreads();
#pragma unroll
    for (int k = 0; k < 5; k++) {
      int j = tid + 256 * k;
      if (j < 1176) {
        int oc = j / 196, p = j - oc * 196;
        const float* wr = s_w + oc * 128 + chunk * 32;
        float s = acc[k];
#pragma unroll
        for (int ic = 0; ic < 32; ic++) s = fmaf(wr[ic], s_in[ic * 200 + p], s);
        acc[k] = s;
      }
    }
  }
#pragma unroll
  for (int k = 0; k < 5; k++) {
    int j = tid + 256 * k;
    if (j < 1176) {
      int oc = j / 196;
      float s = acc[k] + s_b[oc];
      s_sc[j] = s;
      score[b * NA + j] = s;
    }
  }

  // ---- t2: 6 oc x 49 = 294 scores, d2[b] staged fully (linear) ----
  __syncthreads();
  {
    const float* src = d2 + (size_t)b * 6272;
#pragma unroll
    for (int r = 0; r < 7; r++) {
      int e = tid + 256 * r;
      if (e < 1568) *(float4*)(s_in + e * 4) = ((const float4*)src)[e];
    }
  }
  __syncthreads();
#pragma unroll
  for (int k = 0; k < 2; k++) {
    int jj = tid + 256 * k;
    if (jj < 294) {
      int oc = jj / 49, p = jj - oc * 49;
      const float* wr = s_w + 768 + oc * 128;
      float s = s_b[6 + oc];
#pragma unroll 8
      for (int ic = 0; ic < 128; ic++) s = fmaf(wr[ic], s_in[ic * 49 + p], s);
      s_sc[1176 + jj] = s;
      score[b * NA + 1176 + jj] = s;
    }
  }

  // ---- t3: 9 oc x 16 = 144 scores; d3 = relu(p3[0]+p3[1]+bd3) computed inline ----
  __syncthreads();
  {
    const float4* s0 = (const float4*)(p3 + (size_t)b * 2048);
    const float4* s1 = (const float4*)(p3 + 32768 + (size_t)b * 2048);
#pragma unroll
    for (int r = 0; r < 2; r++) {
      int e = tid + 256 * r;
      if (e < 512) {
        float4 a = s0[e], c = s1[e];
        float bb = bd3[e >> 2];
        float4 v;
        v.x = fmaxf(a.x + c.x + bb, 0.f);
        v.y = fmaxf(a.y + c.y + bb, 0.f);
        v.z = fmaxf(a.z + c.z + bb, 0.f);
        v.w = fmaxf(a.w + c.w + bb, 0.f);
        *(float4*)(s_in + e * 4) = v;
      }
    }
  }
  __syncthreads();
  if (tid < 144) {
    int oc = tid >> 4, p = tid & 15;
    const float* wr = s_w + 1536 + oc * 128;
    float s = s_b[12 + oc];
#pragma unroll 8
    for (int ic = 0; ic < 128; ic++) s = fmaf(wr[ic], s_in[ic * 16 + p], s);
    s_sc[1470 + tid] = s;
    score[b * NA + 1470 + tid] = s;
  }
  __syncthreads();

  // ---- NMS: TOPN=4, IoU>0.25 suppress ----
  for (int t = 0; t < 4; t++) {
    float bs = -__builtin_inff();
    int bi = NA;
    for (int i = tid; i < NA; i += 256) {
      float s = s_sc[i];
      if (s > bs || (s == bs && i < bi)) { bs = s; bi = i; }
    }
    r_s[tid] = bs; r_i[tid] = bi;
    __syncthreads();
    for (int off = 128; off > 0; off >>= 1) {
      if (tid < off) {
        float s2 = r_s[tid + off]; int i2 = r_i[tid + off];
        if (s2 > r_s[tid] || (s2 == r_s[tid] && i2 < r_i[tid])) { r_s[tid] = s2; r_i[tid] = i2; }
      }
      __syncthreads();
    }
    const int idx = r_i[0];
    const float by0 = s_bx[idx * 4 + 0], bx0 = s_bx[idx * 4 + 1];
    const float by1 = s_bx[idx * 4 + 2], bx1 = s_bx[idx * 4 + 3];
    if (tid == 0) {
      out_idx[b * 4 + t] = (float)idx;
      out_prob[b * 4 + t] = s_sc[idx];
      sel[(b * 4 + t) * 4 + 0] = by0;
      sel[(b * 4 + t) * 4 + 1] = bx0;
      sel[(b * 4 + t) * 4 + 2] = by1;
      sel[(b * 4 + t) * 4 + 3] = bx1;
    }
    __syncthreads();
    const float a = (by1 - by0) * (bx1 - bx0);
    for (int i = tid; i < NA; i += 256) {
      float cy0 = s_bx[i * 4 + 0], cx0 = s_bx[i * 4 + 1];
      float cy1 = s_bx[i * 4 + 2], cx1 = s_bx[i * 4 + 3];
      float yy0 = fmaxf(by0, cy0), xx0 = fmaxf(bx0, cx0);
      float yy1 = fminf(by1, cy1), xx1 = fminf(bx1, cx1);
      float inter = fmaxf(yy1 - yy0, 0.f) * fmaxf(xx1 - xx0, 0.f);
      float ar = (cy1 - cy0) * (cx1 - cx0);
      float iou = inter / (a + ar - inter);
      if (iou > 0.25f) s_sc[i] = -__builtin_inff();
    }
    __syncthreads();
  }
}

// ---------------- crop+bilinear resize to [16,4,3,224,224], 4 px/thread ----------------
__global__ void crop_kernel(const float* __restrict__ x, const float* __restrict__ sel,
                            float* __restrict__ out) {
  int i4 = blockIdx.x * 256 + threadIdx.x;
  const int total4 = NB * 4 * 3 * 224 * 56;
  if (i4 >= total4) return;
  int px0 = (i4 % 56) * 4;
  int t = i4 / 56;
  int py = t % 224; t /= 224;
  int ch = t % 3;  t /= 3;
  int n  = t % 4;
  int b  = t / 4;

  const float* bx = sel + (b * 4 + n) * 4;
  const float y0 = bx[0], x0 = bx[1], y1 = bx[2], x1 = bx[3];

  float ty = (float)py / 223.0f;
  float cy = y0 + (y1 - 1.0f - y0) * ty;
  float cyf = floorf(cy);
  int ylo = (int)cyf; ylo = ylo < 0 ? 0 : (ylo > 895 ? 895 : ylo);
  int yhi = ylo + 1 > 895 ? 895 : ylo + 1;
  float wy = cy - cyf;

  const float* img = x + ((size_t)b * 3 + ch) * 448 * 448;
  auto g = [&](int yy, int xx) -> float {
    yy -= 224; xx -= 224;
    if ((unsigned)yy < 448u && (unsigned)xx < 448u)
      return img[(size_t)yy * 448 + xx];
    return 0.f;
  };

  float4 res;
  float* rp = &res.x;
#pragma unroll
  for (int k = 0; k < 4; k++) {
    float tx = (float)(px0 + k) / 223.0f;
    float cx = x0 + (x1 - 1.0f - x0) * tx;
    float cxf = floorf(cx);
    int xlo = (int)cxf; xlo = xlo < 0 ? 0 : (xlo > 895 ? 895 : xlo);
    int xhi = xlo + 1 > 895 ? 895 : xlo + 1;
    float wx = cx - cxf;
    float v00 = g(ylo, xlo), v01 = g(ylo, xhi);
    float v10 = g(yhi, xlo), v11 = g(yhi, xhi);
    rp[k] = (1.f - wy) * ((1.f - wx) * v00 + wx * v01) +
            wy * ((1.f - wx) * v10 + wx * v11);
  }
  *(float4*)(out + (size_t)i4 * 4) = res;
}

extern "C" void kernel_launch(void* const* d_in, const int* in_sizes, int n_in,
                              void* d_out, int out_size, void* d_ws, size_t ws_size,
                              hipStream_t stream) {
  const float* x    = (const float*)d_in[0];
  const float* rpn  = (const float*)d_in[1];
  const int*   anc  = (const int*)d_in[2];
  const float* w_d1 = (const float*)d_in[3];
  const float* b_d1 = (const float*)d_in[4];
  const float* w_d2 = (const float*)d_in[5];
  const float* b_d2 = (const float*)d_in[6];
  const float* w_d3 = (const float*)d_in[7];
  const float* b_d3 = (const float*)d_in[8];
  const float* w_t1 = (const float*)d_in[9];
  const float* b_t1 = (const float*)d_in[10];
  const float* w_t2 = (const float*)d_in[11];
  const float* b_t2 = (const float*)d_in[12];
  const float* w_t3 = (const float*)d_in[13];
  const float* b_t3 = (const float*)d_in[14];

  float* out = (float*)d_out;
  float* ws = (float*)d_ws;

  float* d1  = ws;                        // 401408
  float* d2  = d1 + 401408;               // 100352
  float* d3  = d2 + 100352;               // 32768 (unused slot, kept for layout stability)
  float* sel = d3 + 32768;                // 256
  float* p2  = sel + 256;                 // 401408
  float* p3  = p2 + 401408;               // 65536
  unsigned short* wTh = (unsigned short*)(p3 + 65536);   // 2,359,296 ush
  unsigned short* wTl = wTh + 2359296;                   // 2,359,296 ush
  unsigned short* aTh = wTl + 2359296;                   // 6,422,528 ush
  unsigned short* aTl = aTh + 6422528;                   // 6,422,528 ush
  // total ws need: 39,134,208 B (identical to verified layout)

  float* score    = out;                  // 25824
  float* out_idx  = out + 25824;          // 64
  float* out_prob = out + 25888;          // 64
  float* parts    = out + 25952;          // 9,633,792 (final crop output)
  float* p1       = parts;                // 6,422,528 floats scratch; crop overwrites after

  prep<<<dim3(10240), dim3(256), 0, stream>>>(w_d1, rpn, wTh, wTl, aTh, aTl);
  conv1_mfma<<<dim3(512), dim3(256), 0, stream>>>(aTh, aTl, wTh, wTl, p1);
  conv1_finish_p<<<dim3(112), dim3(256), 0, stream>>>(p1, b_d1, d1);
  conv2_part<<<dim3(256), dim3(256), 0, stream>>>(d1, w_d2, p2);
  conv2_finish<<<dim3(392), dim3(256), 0, stream>>>(p2, b_d2, d2);
  conv3_part<<<dim3(256), dim3(256), 0, stream>>>(d2, w_d3, p3);
  score_nms<<<dim3(16), dim3(256), 0, stream>>>(d1, d2, p3, b_d3, w_t1, b_t1, w_t2, b_t2,
                                                w_t3, b_t3, anc, score, out_idx, out_prob, sel);
  crop_kernel<<<dim3(9408), dim3(256), 0, stream>>>(x, sel, parts);
}